// Round 3
// baseline (415.598 us; speedup 1.0000x reference)
//
#include <hip/hip_runtime.h>
#include <hip/hip_bf16.h>

typedef int i32x4  __attribute__((ext_vector_type(4)));
typedef int i32x16 __attribute__((ext_vector_type(16)));

// async global->LDS, 16B per lane; LDS dest = wave-uniform base + lane*16
#define GLL16(g, l) __builtin_amdgcn_global_load_lds( \
    (const __attribute__((address_space(1))) void*)(g), \
    (__attribute__((address_space(3))) void*)(l), 16, 0, 0)

#define CFENCE() asm volatile("" ::: "memory")

// ---------------- abs-sum reduction (for per-tensor mean|w|) ----------------
__global__ __launch_bounds__(256) void abs_sum_kernel(const float* __restrict__ w, int n4,
                                                      double* __restrict__ out)
{
    double acc = 0.0;
    const float4* w4 = (const float4*)w;
    for (int i = blockIdx.x * blockDim.x + threadIdx.x; i < n4; i += gridDim.x * blockDim.x) {
        float4 v = w4[i];
        acc += (double)fabsf(v.x) + (double)fabsf(v.y) + (double)fabsf(v.z) + (double)fabsf(v.w);
    }
    for (int o = 32; o > 0; o >>= 1) acc += __shfl_down(acc, o, 64);
    __shared__ double part[4];
    int lane = threadIdx.x & 63, wv = threadIdx.x >> 6;
    if (lane == 0) part[wv] = acc;
    __syncthreads();
    if (threadIdx.x == 0) atomicAdd(out, part[0] + part[1] + part[2] + part[3]);
}

// ---------------- ternary weight quantization -> i8 {-1,0,1} ----------------
__global__ __launch_bounds__(256) void wquant_kernel(const float* __restrict__ w, int n4,
                                                     const double* __restrict__ sum, double inv_count,
                                                     char* __restrict__ out)
{
    float s = (float)(sum[0] * inv_count);
    s = fmaxf(s, 1e-5f);
    const float4* w4 = (const float4*)w;
    char4* o4 = (char4*)out;
    for (int i = blockIdx.x * blockDim.x + threadIdx.x; i < n4; i += gridDim.x * blockDim.x) {
        float4 v = w4[i];
        char4 c;
        c.x = (char)fminf(fmaxf(rintf(v.x / s), -1.0f), 1.0f);   // rintf = round-half-even
        c.y = (char)fminf(fmaxf(rintf(v.y / s), -1.0f), 1.0f);
        c.z = (char)fminf(fmaxf(rintf(v.z / s), -1.0f), 1.0f);
        c.w = (char)fminf(fmaxf(rintf(v.w / s), -1.0f), 1.0f);
        o4[i] = c;
    }
}

// ---------------- in-register H_16 butterfly helper ----------------
template<int NS>
__device__ __forceinline__ void hreg(float* v)
{
    #pragma unroll
    for (int h = 1; h < (1 << NS); h <<= 1)
        #pragma unroll
        for (int i = 0; i < 16; i++)
            if ((i & h) == 0) { float a = v[i], b = v[i + h]; v[i] = a + b; v[i + h] = a - b; }
}

// ---------------- FWHT + per-token absmax int8 quant (3-phase register FWHT) ----
// Global load is fully coalesced (lane-consecutive float4), redistributed to
// 16-consecutive-per-thread ownership through LDS with a 16B-chunk XOR swizzle
// (chunk ^= (row64>>1)&3 on both write and read -> bank-conflict-free).
// Stage order and all float ops identical to the previous (passing) version.
template<int N, int TOKS>
__global__ __launch_bounds__(256) void fwht_quant_kernel(
    const float* __restrict__ in, long in_stride,
    char* __restrict__ outq, long out_stride,
    float* __restrict__ scales)
{
    constexpr int L = 256 / TOKS;          // threads per token (128 or 256)
    static_assert(N == 16 * L, "N must be 16*threads-per-token");
    __shared__ float sx[TOKS * N];
    __shared__ float red[4];

    const int tid = threadIdx.x;
    const int tk  = tid / L;
    const int lt  = tid % L;
    const long tok = (long)blockIdx.x * TOKS + tk;
    const float* row = in + tok * in_stride;
    float* s = sx + tk * N;

    // coalesced load: thread lt loads float4 indices {lt + L*i}, i = 0..3
    float4 a[4];
    {
        const float4* r4 = (const float4*)row;
        #pragma unroll
        for (int i = 0; i < 4; i++) a[i] = r4[lt + L * i];
    }
    // staged LDS write: f4 j = lt+L*i -> row64 = j>>2 (64B rows), chunk c = lt&3;
    // phys chunk = c ^ ((row64>>1)&3) = (lt&3) ^ ((lt>>3)&3)  (i-independent)
    {
        const int c  = lt & 3;
        const int pc = (c ^ ((lt >> 3) & 3)) << 2;   // float offset within row
        #pragma unroll
        for (int i = 0; i < 4; i++) {
            const int r64 = (lt >> 2) + (L >> 2) * i;
            *(float4*)(s + r64 * 16 + pc) = a[i];
        }
    }
    __syncthreads();

    // redistribution read: thread lt owns row64 = lt (its 16 consecutive floats)
    float v[16];
    {
        const int sw = (lt >> 1) & 3;
        #pragma unroll
        for (int c = 0; c < 4; c++) {
            float4 t = *(const float4*)(s + lt * 16 + ((c ^ sw) << 2));
            v[4*c] = t.x; v[4*c+1] = t.y; v[4*c+2] = t.z; v[4*c+3] = t.w;
        }
    }
    hreg<4>(v);                            // h = 1,2,4,8
    // phase-1 output (linear layout); same 64B row this thread just read -> no hazard
    #pragma unroll
    for (int i = 0; i < 4; i++)
        *(float4*)(s + lt * 16 + 4 * i) = make_float4(v[4*i], v[4*i+1], v[4*i+2], v[4*i+3]);
    __syncthreads();

    const int o = lt & 15, ss = lt >> 4;
    #pragma unroll
    for (int j = 0; j < 16; j++) v[j] = s[o + 256 * ss + 16 * j];
    hreg<(L == 256) ? 4 : 3>(v);           // h = 16..128 (L=256) or 16..64 (L=128)
    #pragma unroll
    for (int j = 0; j < 16; j++) s[o + 256 * ss + 16 * j] = v[j];
    __syncthreads();

    #pragma unroll
    for (int j = 0; j < 16; j++) v[j] = s[o + 16 * ss + L * j];
    hreg<4>(v);                            // top 4 stages

    const float rn = 1.0f / sqrtf((float)N);
    float m = 0.0f;
    #pragma unroll
    for (int j = 0; j < 16; j++) { v[j] *= rn; m = fmaxf(m, fabsf(v[j])); }
    for (int off = 32; off > 0; off >>= 1) m = fmaxf(m, __shfl_down(m, off, 64));
    if ((tid & 63) == 0) red[tid >> 6] = m;
    __syncthreads();
    float mm;
    if (TOKS == 1) mm = fmaxf(fmaxf(red[0], red[1]), fmaxf(red[2], red[3]));
    else           mm = fmaxf(red[2 * tk], red[2 * tk + 1]);
    mm = fmaxf(mm, 1e-5f);
    const float sc = 127.0f / mm;
    if (lt == 0) scales[tok] = sc;
    __syncthreads();                       // sx about to be reused as i8 buffer

    char* ct = (char*)sx + tk * N;
    #pragma unroll
    for (int j = 0; j < 16; j++) {
        float q = fminf(fmaxf(rintf(v[j] * sc), -127.0f), 127.0f);
        ct[o + 16 * ss + L * j] = (char)q;
    }
    __syncthreads();
    int4* dst = (int4*)(outq + tok * out_stride);
    dst[lt] = ((const int4*)ct)[lt];
}

// ---------------- i8 MFMA GEMM, 256x256 tile, 8 waves, mfma_i32_32x32x32_i8 ----
// C[t][o] = sum_k A[t][k]*B[o][k], fused dequant epilogue (+ optional relu^2).
// K-tile = 64 i8. Ring of 4 LDS buffers; tile t+3 staged while tile t computes;
// ONE barrier + counted vmcnt(8) per K-tile (loads span 3 tiles of compute).
// LDS XOR swizzle: pre-swizzled global source + swizzled ds_read (dest linear).
#define BM2 256
#define BN2 256
#define BK2 64

__global__ __launch_bounds__(512, 2) void gemm_bt_kernel(
    const char* __restrict__ A, int lda,
    const char* __restrict__ B, int ldb,
    float* __restrict__ C, int ldc,
    int K, int lognx,
    const float* __restrict__ sx,
    const double* __restrict__ wsum, double inv_count,
    int do_relu2)
{
    __shared__ __align__(16) char As[4][BM2 * BK2];   // 4 x 16 KB
    __shared__ __align__(16) char Bs[4][BN2 * BK2];   // 4 x 16 KB

    // XCD row-band swizzle (grid % 8 == 0 -> bijective)
    const int bid = blockIdx.x;
    const int xcd = bid & 7;
    const int n = bid >> 3;
    const int nper = gridDim.x >> 3;
    const int bx = n & ((1 << lognx) - 1);
    const int by = xcd * (nper >> lognx) + (n >> lognx);
    const int row0 = by * BM2;
    const int col0 = bx * BN2;

    const int tid = threadIdx.x;
    const int lane = tid & 63;
    const int w = tid >> 6;          // 8 waves
    const int wr = w >> 2;           // 0..1 : 128-row band
    const int wc = w & 3;            // 0..3 : 64-col band

    i32x16 acc[4][2] = {};           // 4 row-tiles x 2 col-tiles of 32x32

    // ---- staging addressing: linear LDS dest, swizzled global source ----
    const int srow = w * 16 + (lane >> 2);
    const int sseg = ((lane & 3) ^ ((lane >> 3) & 3)) << 4;
    const char* Ag0 = A + (size_t)(row0 + srow) * lda + sseg;
    const char* Ag1 = Ag0 + (size_t)128 * lda;
    const char* Bg0 = B + (size_t)(col0 + srow) * ldb + sseg;
    const char* Bg1 = Bg0 + (size_t)128 * ldb;
    const int wdst = w * 1024;       // wave chunk within one 8 KB GLL round

    // ---- fragment read addressing (32x32x32: row = lane&31, k-seg = lane>>5) ----
    const int r31 = lane & 31;
    const int ksel = lane >> 5;                      // 0..1
    const int fsw = (r31 >> 1) & 3;                  // row-bit swizzle (tile bases % 8 == 0)
    const int abase = (wr * 128 + r31) * BK2;        // + i*32*BK2
    const int bbase = (wc * 64  + r31) * BK2;        // + j*32*BK2

    const int NT = K >> 6;           // 32 (GEMM1) / 64 (GEMM2)

    auto stage = [&](int tt) {
        const int sb = tt & 3;
        const int ko = tt * BK2;
        GLL16(Ag0 + ko, &As[sb][wdst]);
        GLL16(Ag1 + ko, &As[sb][wdst + 8192]);
        GLL16(Bg0 + ko, &Bs[sb][wdst]);
        GLL16(Bg1 + ko, &Bs[sb][wdst + 8192]);
    };
    auto compute = [&](int t) __attribute__((always_inline)) {
        const int cb = t & 3;
        const char* as = As[cb];
        const char* bs = Bs[cb];
        i32x4 af[4][2], bf[2][2];
        #pragma unroll
        for (int i = 0; i < 4; ++i)
            #pragma unroll
            for (int p = 0; p < 2; ++p)
                af[i][p] = *(const i32x4*)(as + abase + i * 32 * BK2 + (((2 * p + ksel) ^ fsw) << 4));
        #pragma unroll
        for (int j = 0; j < 2; ++j)
            #pragma unroll
            for (int p = 0; p < 2; ++p)
                bf[j][p] = *(const i32x4*)(bs + bbase + j * 32 * BK2 + (((2 * p + ksel) ^ fsw) << 4));
        __builtin_amdgcn_s_setprio(1);
        #pragma unroll
        for (int p = 0; p < 2; ++p)
            #pragma unroll
            for (int i = 0; i < 4; ++i)
                #pragma unroll
                for (int j = 0; j < 2; ++j)
                    acc[i][j] = __builtin_amdgcn_mfma_i32_32x32x32_i8(af[i][p], bf[j][p], acc[i][j], 0, 0, 0);
        __builtin_amdgcn_s_setprio(0);
    };

    // prologue: tiles 0,1,2 in flight (12 loads/wave); wait tile 0 (8 remain)
    stage(0); stage(1); stage(2);
    asm volatile("s_waitcnt vmcnt(8)" ::: "memory");
    __builtin_amdgcn_s_barrier();
    CFENCE();

    for (int t = 0; t <= NT - 4; ++t) {
        stage(t + 3);                // writes buffer freed at the last barrier
        compute(t);
        asm volatile("s_waitcnt vmcnt(8)" ::: "memory");   // tile t+1 landed
        __builtin_amdgcn_s_barrier();
        CFENCE();
    }
    compute(NT - 3);
    asm volatile("s_waitcnt vmcnt(4)" ::: "memory");       // tile NT-2 landed
    __builtin_amdgcn_s_barrier();
    CFENCE();
    compute(NT - 2);
    asm volatile("s_waitcnt vmcnt(0)" ::: "memory");       // tile NT-1 landed
    __builtin_amdgcn_s_barrier();
    CFENCE();
    compute(NT - 1);

    // epilogue: out = (float)acc * s_w / scale_x[row]; optional relu^2
    // 32x32 C/D layout: col = lane&31, row = (reg&3) + 8*(reg>>2) + 4*(lane>>5)
    float sw = (float)(wsum[0] * inv_count);
    sw = fmaxf(sw, 1e-5f);
    #pragma unroll
    for (int i = 0; i < 4; ++i) {
        #pragma unroll
        for (int reg = 0; reg < 16; ++reg) {
            const int rowm = row0 + wr * 128 + i * 32 + (reg & 3) + 8 * (reg >> 2) + 4 * ksel;
            const float esc = sw / sx[rowm];
            float* crow = C + (size_t)rowm * ldc + col0 + wc * 64 + r31;
            #pragma unroll
            for (int j = 0; j < 2; ++j) {
                float v = (float)acc[i][j][reg] * esc;
                if (do_relu2) { v = fmaxf(v, 0.0f); v = v * v; }
                crow[j * 32] = v;
            }
        }
    }
}

extern "C" void kernel_launch(void* const* d_in, const int* in_sizes, int n_in,
                              void* d_out, int out_size, void* d_ws, size_t ws_size,
                              hipStream_t stream)
{
    const float* X   = (const float*)d_in[0];   // (4,2048,2048) f32
    const float* Wup = (const float*)d_in[1];   // (4096,2048)   f32
    const float* Wdn = (const float*)d_in[2];   // (2048,4096)   f32
    float* out = (float*)d_out;                 // (4,2048,2048) f32

    const int Mtok = 8192, H = 2048, I = 4096;
    const int NW = H * I;                       // 8388608 = 2^23 weights per tensor

    // workspace layout
    char* ws = (char*)d_ws;
    double* sums = (double*)ws;                                  // 2 doubles
    float* sx1 = (float*)(ws + 1024);                            // 8192 f32
    float* sx2 = (float*)(ws + 1024 + 32768);                    // 8192 f32
    char* wqup = ws + (1 << 20);                                 // 8.4 MB (i8)
    char* wqdn = wqup + (size_t)NW;                              // 8.4 MB
    char* xq1  = wqdn + (size_t)NW;                              // 16.8 MB (i8)
    float* hbuf = (float*)(xq1 + (size_t)Mtok * H);              // 134 MB (h f32; xq2 i8 overlaid per-row)

    hipMemsetAsync(sums, 0, 16, stream);
    abs_sum_kernel<<<512, 256, 0, stream>>>(Wup, NW / 4, &sums[0]);
    abs_sum_kernel<<<512, 256, 0, stream>>>(Wdn, NW / 4, &sums[1]);
    const double invc = 1.0 / (double)NW;       // exactly 2^-23
    wquant_kernel<<<1024, 256, 0, stream>>>(Wup, NW / 4, &sums[0], invc, wqup);
    wquant_kernel<<<1024, 256, 0, stream>>>(Wdn, NW / 4, &sums[1], invc, wqdn);

    // stage 1: FWHT(H=2048) + quant, 2 tokens/block
    fwht_quant_kernel<2048, 2><<<Mtok / 2, 256, 0, stream>>>(X, H, xq1, H, sx1);
    // GEMM1 + relu^2 fused -> hbuf (f32, ld=I); grid 32x16 tiles -> 1-D swizzled, lognx=4
    gemm_bt_kernel<<<(I / BN2) * (Mtok / BM2), 512, 0, stream>>>(
        xq1, H, wqup, H, hbuf, I, H, 4, sx1, &sums[0], invc, 1);
    // stage 2: FWHT(I=4096) + quant; xq2 (i8) overlaid on hbuf rows (stride 4*I bytes)
    fwht_quant_kernel<4096, 1><<<Mtok, 256, 0, stream>>>(hbuf, I, (char*)hbuf, 4 * I, sx2);
    // GEMM2 -> out; grid 32x8 tiles -> 1-D swizzled, lognx=3
    gemm_bt_kernel<<<(H / BN2) * (Mtok / BM2), 512, 0, stream>>>(
        (const char*)hbuf, 4 * I, wqdn, I, out, H, I, 3, sx2, &sums[1], invc, 0);
}

// Round 5
// 372.310 us; speedup vs baseline: 1.1163x; 1.1163x over previous
//
#include <hip/hip_runtime.h>
#include <hip/hip_bf16.h>
#include <hip/hip_fp16.h>

typedef int i32x4 __attribute__((ext_vector_type(4)));

// async global->LDS, 16B per lane; LDS dest = wave-uniform base + lane*16
#define GLL16(g, l) __builtin_amdgcn_global_load_lds( \
    (const __attribute__((address_space(1))) void*)(g), \
    (__attribute__((address_space(3))) void*)(l), 16, 0, 0)

#define CFENCE() asm volatile("" ::: "memory")

// ---------------- abs-sum reduction for BOTH weight tensors (fused) ----------------
__global__ __launch_bounds__(256) void abs_sum2_kernel(const float* __restrict__ w0,
                                                       const float* __restrict__ w1, int n4,
                                                       double* __restrict__ out)
{
    const int sel = blockIdx.x & 1;
    const float4* w4 = (const float4*)(sel ? w1 : w0);
    const int b = blockIdx.x >> 1, nb = gridDim.x >> 1;
    double acc = 0.0;
    for (int i = b * blockDim.x + threadIdx.x; i < n4; i += nb * blockDim.x) {
        float4 v = w4[i];
        acc += (double)fabsf(v.x) + (double)fabsf(v.y) + (double)fabsf(v.z) + (double)fabsf(v.w);
    }
    for (int o = 32; o > 0; o >>= 1) acc += __shfl_down(acc, o, 64);
    __shared__ double part[4];
    int lane = threadIdx.x & 63, wv = threadIdx.x >> 6;
    if (lane == 0) part[wv] = acc;
    __syncthreads();
    if (threadIdx.x == 0) atomicAdd(&out[sel], part[0] + part[1] + part[2] + part[3]);
}

// ---------------- ternary weight quantization -> i8 {-1,0,1}, both tensors ---------
__global__ __launch_bounds__(256) void wquant2_kernel(const float* __restrict__ w0,
                                                      const float* __restrict__ w1, int n4,
                                                      const double* __restrict__ sums, double inv_count,
                                                      char* __restrict__ o0, char* __restrict__ o1)
{
    const int sel = blockIdx.x & 1;
    const float4* w4 = (const float4*)(sel ? w1 : w0);
    char4* o4 = (char4*)(sel ? o1 : o0);
    float s = (float)(sums[sel] * inv_count);
    s = fmaxf(s, 1e-5f);
    const int b = blockIdx.x >> 1, nb = gridDim.x >> 1;
    for (int i = b * blockDim.x + threadIdx.x; i < n4; i += nb * blockDim.x) {
        float4 v = w4[i];
        char4 c;
        c.x = (char)fminf(fmaxf(rintf(v.x / s), -1.0f), 1.0f);   // rintf = round-half-even
        c.y = (char)fminf(fmaxf(rintf(v.y / s), -1.0f), 1.0f);
        c.z = (char)fminf(fmaxf(rintf(v.z / s), -1.0f), 1.0f);
        c.w = (char)fminf(fmaxf(rintf(v.w / s), -1.0f), 1.0f);
        o4[i] = c;
    }
}

// ---------------- in-register H_16 butterfly helper ----------------
template<int NS>
__device__ __forceinline__ void hreg(float* v)
{
    #pragma unroll
    for (int h = 1; h < (1 << NS); h <<= 1)
        #pragma unroll
        for (int i = 0; i < 16; i++)
            if ((i & h) == 0) { float a = v[i], b = v[i + h]; v[i] = a + b; v[i + h] = a - b; }
}

// LDS element swizzle: logical float index e -> physical float index.
// 16-float rows; chunk (4 floats) XORed with (row>>1)&3.
// Fixes the 32-way bank conflict of the linear phase-1 write (all even lanes
// previously hit one 4-bank group); write side becomes 2-way (free, m136).
__device__ __forceinline__ int lswz(int e)
{
    const int r16 = e >> 4;
    return r16 * 16 + 4 * (((e >> 2) & 3) ^ ((r16 >> 1) & 3)) + (e & 3);
}

// ---------------- FWHT + per-token absmax int8 quant (3-phase register FWHT) ----
// Stages applied in ascending h order; float ops identical to the verified
// version -> bit-exact. Only the LDS layout is swizzled (lswz).
template<int N, int TOKS>
__global__ __launch_bounds__(256) void fwht_quant_kernel(
    const float* __restrict__ in, long in_stride,
    char* __restrict__ outq, long out_stride,
    float* __restrict__ scales)
{
    constexpr int L = 256 / TOKS;          // threads per token (128 or 256)
    static_assert(N == 16 * L, "N must be 16*threads-per-token");
    __shared__ float sx[TOKS * N];
    __shared__ float red[4];

    const int tid = threadIdx.x;
    const int tk  = tid / L;
    const int lt  = tid % L;
    const long tok = (long)blockIdx.x * TOKS + tk;
    const float* row = in + tok * in_stride;
    float* s = sx + tk * N;

    float v[16];
    {
        const float4* r4 = (const float4*)(row + (size_t)lt * 16);
        float4 a[4];
        #pragma unroll
        for (int i = 0; i < 4; i++) a[i] = r4[i];
        #pragma unroll
        for (int i = 0; i < 4; i++) {
            v[4*i] = a[i].x; v[4*i+1] = a[i].y; v[4*i+2] = a[i].z; v[4*i+3] = a[i].w;
        }
    }
    hreg<4>(v);                            // h = 1,2,4,8
    {
        const int psw = (lt >> 1) & 3;     // == (row16>>1)&3 for row16 = lt
        #pragma unroll
        for (int i = 0; i < 4; i++)
            *(float4*)(s + lt * 16 + 4 * (i ^ psw)) =
                make_float4(v[4*i], v[4*i+1], v[4*i+2], v[4*i+3]);
    }
    __syncthreads();

    const int o = lt & 15, ss = lt >> 4;
    #pragma unroll
    for (int j = 0; j < 16; j++) v[j] = s[lswz(o + 256 * ss + 16 * j)];
    hreg<(L == 256) ? 4 : 3>(v);           // h = 16..128 (L=256) or 16..64 (L=128)
    #pragma unroll
    for (int j = 0; j < 16; j++) s[lswz(o + 256 * ss + 16 * j)] = v[j];
    __syncthreads();

    #pragma unroll
    for (int j = 0; j < 16; j++) v[j] = s[lswz(o + 16 * ss + L * j)];
    hreg<4>(v);                            // top 4 stages

    const float rn = 1.0f / sqrtf((float)N);
    float m = 0.0f;
    #pragma unroll
    for (int j = 0; j < 16; j++) { v[j] *= rn; m = fmaxf(m, fabsf(v[j])); }
    for (int off = 32; off > 0; off >>= 1) m = fmaxf(m, __shfl_down(m, off, 64));
    if ((tid & 63) == 0) red[tid >> 6] = m;
    __syncthreads();
    float mm;
    if (TOKS == 1) mm = fmaxf(fmaxf(red[0], red[1]), fmaxf(red[2], red[3]));
    else           mm = fmaxf(red[2 * tk], red[2 * tk + 1]);
    mm = fmaxf(mm, 1e-5f);
    const float sc = 127.0f / mm;
    if (lt == 0) scales[tok] = sc;
    __syncthreads();                       // sx about to be reused as i8 buffer

    // quantize from registers, repack through LDS (as i8, linear) for 16B stores
    char* ct = (char*)sx + tk * N;
    #pragma unroll
    for (int j = 0; j < 16; j++) {
        float q = fminf(fmaxf(rintf(v[j] * sc), -127.0f), 127.0f);
        ct[o + 16 * ss + L * j] = (char)q;
    }
    __syncthreads();
    int4* dst = (int4*)(outq + tok * out_stride);
    dst[lt] = ((const int4*)ct)[lt];
}

// ---------------- FWHT + quant, f16 input (N=4096, 1 token/block) ----------------
// f16 rows: thread lt's 16 consecutive elems = 32 contiguous bytes -> the direct
// load is fully coalesced; no staging bounce needed. Body identical to above.
__global__ __launch_bounds__(256) void fwht_quant_f16_kernel(
    const __half* __restrict__ in, long in_stride,
    char* __restrict__ outq, long out_stride,
    float* __restrict__ scales)
{
    constexpr int N = 4096, L = 256;
    __shared__ float sx[N];
    __shared__ float red[4];

    const int lt = threadIdx.x;
    const long tok = blockIdx.x;
    const __half* row = in + tok * in_stride;
    float* s = sx;

    float v[16];
    {
        const int4* r4 = (const int4*)row;
        int4 q0 = r4[2 * lt], q1 = r4[2 * lt + 1];
        const __half2* h0 = (const __half2*)&q0;
        const __half2* h1 = (const __half2*)&q1;
        #pragma unroll
        for (int i = 0; i < 4; i++) {
            float2 f = __half22float2(h0[i]);
            v[2*i] = f.x; v[2*i+1] = f.y;
        }
        #pragma unroll
        for (int i = 0; i < 4; i++) {
            float2 f = __half22float2(h1[i]);
            v[8+2*i] = f.x; v[8+2*i+1] = f.y;
        }
    }
    hreg<4>(v);                            // h = 1,2,4,8
    {
        const int psw = (lt >> 1) & 3;
        #pragma unroll
        for (int i = 0; i < 4; i++)
            *(float4*)(s + lt * 16 + 4 * (i ^ psw)) =
                make_float4(v[4*i], v[4*i+1], v[4*i+2], v[4*i+3]);
    }
    __syncthreads();

    const int o = lt & 15, ss = lt >> 4;
    #pragma unroll
    for (int j = 0; j < 16; j++) v[j] = s[lswz(o + 256 * ss + 16 * j)];
    hreg<4>(v);                            // h = 16..128
    #pragma unroll
    for (int j = 0; j < 16; j++) s[lswz(o + 256 * ss + 16 * j)] = v[j];
    __syncthreads();

    #pragma unroll
    for (int j = 0; j < 16; j++) v[j] = s[lswz(o + 16 * ss + L * j)];
    hreg<4>(v);                            // h = 256..2048

    const float rn = 1.0f / sqrtf((float)N);
    float m = 0.0f;
    #pragma unroll
    for (int j = 0; j < 16; j++) { v[j] *= rn; m = fmaxf(m, fabsf(v[j])); }
    for (int off = 32; off > 0; off >>= 1) m = fmaxf(m, __shfl_down(m, off, 64));
    if ((lt & 63) == 0) red[lt >> 6] = m;
    __syncthreads();
    float mm = fmaxf(fmaxf(red[0], red[1]), fmaxf(red[2], red[3]));
    mm = fmaxf(mm, 1e-5f);
    const float sc = 127.0f / mm;
    if (lt == 0) scales[tok] = sc;
    __syncthreads();                       // sx about to be reused as i8 buffer

    char* ct = (char*)sx;
    #pragma unroll
    for (int j = 0; j < 16; j++) {
        float q = fminf(fmaxf(rintf(v[j] * sc), -127.0f), 127.0f);
        ct[o + 16 * ss + L * j] = (char)q;
    }
    __syncthreads();
    int4* dst = (int4*)(outq + tok * out_stride);
    dst[lt] = ((const int4*)ct)[lt];
}

// ---------------- i8 MFMA GEMM, 256x256 tile, 8 waves, 2-phase/K-tile pipeline ----
// (best verified schedule; epilogue can emit f32 or f16)
#define BM2 256
#define BN2 256
#define BK2 64

__global__ __launch_bounds__(512, 2) void gemm_bt_kernel(
    const char* __restrict__ A, int lda,
    const char* __restrict__ B, int ldb,
    void* __restrict__ Cv, int ldc,
    int K, int lognx,
    const float* __restrict__ sx,
    const double* __restrict__ wsum, double inv_count,
    int do_relu2, int out_f16)
{
    __shared__ __align__(16) char As[4][BM2 * BK2];   // 4 x 16 KB
    __shared__ __align__(16) char Bs[4][BN2 * BK2];   // 4 x 16 KB

    // XCD row-band swizzle (grid % 8 == 0 -> bijective)
    const int bid = blockIdx.x;
    const int xcd = bid & 7;
    const int n = bid >> 3;
    const int nper = gridDim.x >> 3;
    const int bx = n & ((1 << lognx) - 1);
    const int by = xcd * (nper >> lognx) + (n >> lognx);
    const int row0 = by * BM2;
    const int col0 = bx * BN2;

    const int tid = threadIdx.x;
    const int lane = tid & 63;
    const int w = tid >> 6;          // 8 waves
    const int wr = w >> 2;           // 0..1 : 128-row band
    const int wc = w & 3;            // 0..3 : 64-col band

    i32x4 acc[8][4] = {};

    // ---- staging addressing: linear LDS dest, swizzled global source ----
    const int srow = w * 16 + (lane >> 2);
    const int sseg = ((lane & 3) ^ ((lane >> 3) & 3)) << 4;
    const char* Ag0 = A + (size_t)(row0 + srow) * lda + sseg;
    const char* Ag1 = Ag0 + (size_t)128 * lda;
    const char* Bg0 = B + (size_t)(col0 + srow) * ldb + sseg;
    const char* Bg1 = Bg0 + (size_t)128 * ldb;
    const int wdst = w * 1024;       // wave chunk within one 8 KB GLL round

    // ---- fragment read addressing (swizzled) ----
    const int fr = lane & 15;
    const int fks = lane >> 4;
    const int rsw = ((fks ^ ((fr >> 1) & 3)) << 4);
    const int aoff = (wr * 128 + fr) * BK2 + rsw;    // + i*1024
    const int boff = (wc * 64  + fr) * BK2 + rsw;    // + j*1024

    const int NT = K >> 6;           // 32 (GEMM1) / 64 (GEMM2)

    auto stageA = [&](int tt) {
        const int sb = tt & 3;
        const int ko = tt * BK2;
        GLL16(Ag0 + ko, &As[sb][wdst]);
        GLL16(Ag1 + ko, &As[sb][wdst + 8192]);
    };
    auto stageB = [&](int tt) {
        const int sb = tt & 3;
        const int ko = tt * BK2;
        GLL16(Bg0 + ko, &Bs[sb][wdst]);
        GLL16(Bg1 + ko, &Bs[sb][wdst + 8192]);
    };

    // one K-tile, 2 phases; staging of tile t+3 interleaved when STAGE
    auto tile_body = [&](int t, bool do_stage) __attribute__((always_inline)) {
        const int cb = t & 3;
        const char* as = As[cb];
        const char* bs = Bs[cb];
        i32x4 af[4], bf[4], af2[4];
        // ---- phase 0: rows 0-3 x cols 0-3 ----
        #pragma unroll
        for (int i = 0; i < 4; ++i) af[i] = *(const i32x4*)(as + aoff + i * 1024);
        #pragma unroll
        for (int j = 0; j < 4; ++j) bf[j] = *(const i32x4*)(bs + boff + j * 1024);
        if (do_stage) stageA(t + 3);
        __builtin_amdgcn_s_barrier();
        CFENCE();
        __builtin_amdgcn_s_setprio(1);
        #pragma unroll
        for (int i = 0; i < 4; ++i)
            #pragma unroll
            for (int j = 0; j < 4; ++j)
                acc[i][j] = __builtin_amdgcn_mfma_i32_16x16x64_i8(af[i], bf[j], acc[i][j], 0, 0, 0);
        __builtin_amdgcn_s_setprio(0);
        __builtin_amdgcn_s_barrier();
        CFENCE();
        // ---- phase 1: rows 4-7 x cols 0-3 (bf held in regs) ----
        #pragma unroll
        for (int i = 0; i < 4; ++i) af2[i] = *(const i32x4*)(as + aoff + (4 + i) * 1024);
        if (do_stage) stageB(t + 3);
        __builtin_amdgcn_s_barrier();
        CFENCE();
        __builtin_amdgcn_s_setprio(1);
        #pragma unroll
        for (int i = 0; i < 4; ++i)
            #pragma unroll
            for (int j = 0; j < 4; ++j)
                acc[4 + i][j] = __builtin_amdgcn_mfma_i32_16x16x64_i8(af2[i], bf[j], acc[4 + i][j], 0, 0, 0);
        __builtin_amdgcn_s_setprio(0);
    };

    // prologue: tiles 0,1,2 in flight (12 loads/wave); wait tile 0 (8 remain)
    stageA(0); stageB(0); stageA(1); stageB(1); stageA(2); stageB(2);
    asm volatile("s_waitcnt vmcnt(8)" ::: "memory");
    __builtin_amdgcn_s_barrier();
    CFENCE();

    for (int t = 0; t <= NT - 4; ++t) {
        tile_body(t, true);
        asm volatile("s_waitcnt vmcnt(8)" ::: "memory");   // tile t+1 landed
        __builtin_amdgcn_s_barrier();
        CFENCE();
    }
    tile_body(NT - 3, false);
    asm volatile("s_waitcnt vmcnt(4)" ::: "memory");       // tile NT-2 landed
    __builtin_amdgcn_s_barrier();
    CFENCE();
    tile_body(NT - 2, false);
    asm volatile("s_waitcnt vmcnt(0)" ::: "memory");       // tile NT-1 landed
    __builtin_amdgcn_s_barrier();
    CFENCE();
    tile_body(NT - 1, false);

    // epilogue: out = (float)acc * s_w / scale_x[row]; optional relu^2; f32 or f16
    float sw = (float)(wsum[0] * inv_count);
    sw = fmaxf(sw, 1e-5f);
    const int qd = lane >> 4;
    if (out_f16) {
        __half* C = (__half*)Cv;
        #pragma unroll
        for (int i = 0; i < 8; ++i) {
            #pragma unroll
            for (int r = 0; r < 4; ++r) {
                int rowm = row0 + wr * 128 + i * 16 + qd * 4 + r;
                float esc = sw / sx[rowm];
                __half* crow = C + (size_t)rowm * ldc + col0 + wc * 64;
                #pragma unroll
                for (int j = 0; j < 4; ++j) {
                    float v = (float)acc[i][j][r] * esc;
                    if (do_relu2) { v = fmaxf(v, 0.0f); v = v * v; }
                    crow[j * 16 + fr] = __float2half(v);
                }
            }
        }
    } else {
        float* C = (float*)Cv;
        #pragma unroll
        for (int i = 0; i < 8; ++i) {
            #pragma unroll
            for (int r = 0; r < 4; ++r) {
                int rowm = row0 + wr * 128 + i * 16 + qd * 4 + r;
                float esc = sw / sx[rowm];
                float* crow = C + (size_t)rowm * ldc + col0 + wc * 64;
                #pragma unroll
                for (int j = 0; j < 4; ++j) {
                    float v = (float)acc[i][j][r] * esc;
                    if (do_relu2) { v = fmaxf(v, 0.0f); v = v * v; }
                    crow[j * 16 + fr] = v;
                }
            }
        }
    }
}

extern "C" void kernel_launch(void* const* d_in, const int* in_sizes, int n_in,
                              void* d_out, int out_size, void* d_ws, size_t ws_size,
                              hipStream_t stream)
{
    const float* X   = (const float*)d_in[0];   // (4,2048,2048) f32
    const float* Wup = (const float*)d_in[1];   // (4096,2048)   f32
    const float* Wdn = (const float*)d_in[2];   // (2048,4096)   f32
    float* out = (float*)d_out;                 // (4,2048,2048) f32

    const int Mtok = 8192, H = 2048, I = 4096;
    const int NW = H * I;                       // 8388608 = 2^23 weights per tensor

    // workspace layout
    char* ws = (char*)d_ws;
    double* sums = (double*)ws;                                  // 2 doubles
    float* sx1 = (float*)(ws + 1024);                            // 8192 f32
    float* sx2 = (float*)(ws + 1024 + 32768);                    // 8192 f32
    char* wqup = ws + (1 << 20);                                 // 8.4 MB (i8)
    char* wqdn = wqup + (size_t)NW;                              // 8.4 MB
    char* xq1  = wqdn + (size_t)NW;                              // 16.8 MB (i8)
    char* hbuf = xq1 + (size_t)Mtok * H;                         // 67 MB (h f16; xq2 i8 overlaid per-row)

    hipMemsetAsync(sums, 0, 16, stream);
    abs_sum2_kernel<<<1024, 256, 0, stream>>>(Wup, Wdn, NW / 4, sums);
    const double invc = 1.0 / (double)NW;       // exactly 2^-23
    wquant2_kernel<<<2048, 256, 0, stream>>>(Wup, Wdn, NW / 4, sums, invc, wqup, wqdn);

    // stage 1: FWHT(H=2048) + quant, 2 tokens/block
    fwht_quant_kernel<2048, 2><<<Mtok / 2, 256, 0, stream>>>(X, H, xq1, H, sx1);
    // GEMM1 + relu^2 fused -> hbuf (f16, ld=I); grid 32x16 tiles -> 1-D swizzled, lognx=4
    gemm_bt_kernel<<<(I / BN2) * (Mtok / BM2), 512, 0, stream>>>(
        xq1, H, wqup, H, hbuf, I, H, 4, sx1, &sums[0], invc, 1, 1);
    // stage 2: FWHT(I=4096) from f16 + quant; xq2 (i8) overlaid on hbuf rows (stride 2*I bytes)
    fwht_quant_f16_kernel<<<Mtok, 256, 0, stream>>>((const __half*)hbuf, I, hbuf, 2 * I, sx2);
    // GEMM2 -> out (f32); grid 32x8 tiles -> 1-D swizzled, lognx=3
    gemm_bt_kernel<<<(H / BN2) * (Mtok / BM2), 512, 0, stream>>>(
        (const char*)hbuf, 2 * I, wqdn, I, out, H, I, 3, sx2, &sums[1], invc, 0, 0);
}

// Round 6
// 362.406 us; speedup vs baseline: 1.1468x; 1.0273x over previous
//
#include <hip/hip_runtime.h>
#include <hip/hip_bf16.h>
#include <hip/hip_fp16.h>

typedef int i32x4 __attribute__((ext_vector_type(4)));

// async global->LDS, 16B per lane; LDS dest = wave-uniform base + lane*16
#define GLL16(g, l) __builtin_amdgcn_global_load_lds( \
    (const __attribute__((address_space(1))) void*)(g), \
    (__attribute__((address_space(3))) void*)(l), 16, 0, 0)

#define CFENCE() asm volatile("" ::: "memory")

// ---------------- abs-sum reduction for BOTH weight tensors (fused) ----------------
__global__ __launch_bounds__(256) void abs_sum2_kernel(const float* __restrict__ w0,
                                                       const float* __restrict__ w1, int n4,
                                                       double* __restrict__ out)
{
    const int sel = blockIdx.x & 1;
    const float4* w4 = (const float4*)(sel ? w1 : w0);
    const int b = blockIdx.x >> 1, nb = gridDim.x >> 1;
    double acc = 0.0;
    for (int i = b * blockDim.x + threadIdx.x; i < n4; i += nb * blockDim.x) {
        float4 v = w4[i];
        acc += (double)fabsf(v.x) + (double)fabsf(v.y) + (double)fabsf(v.z) + (double)fabsf(v.w);
    }
    for (int o = 32; o > 0; o >>= 1) acc += __shfl_down(acc, o, 64);
    __shared__ double part[4];
    int lane = threadIdx.x & 63, wv = threadIdx.x >> 6;
    if (lane == 0) part[wv] = acc;
    __syncthreads();
    if (threadIdx.x == 0) atomicAdd(&out[sel], part[0] + part[1] + part[2] + part[3]);
}

// ---------------- ternary weight quantization -> i8 {-1,0,1}, both tensors ---------
// clip(rint(v/s),-1,1) == (|v| > 0.5*s) ? sign(v) : 0   (rint is half-even: 0.5->0,
// 1.5->2->clip 1; equality |v|==0.5s -> 0, matched by strict >). No fdiv needed.
__global__ __launch_bounds__(256) void wquant2_kernel(const float* __restrict__ w0,
                                                      const float* __restrict__ w1, int n4,
                                                      const double* __restrict__ sums, double inv_count,
                                                      char* __restrict__ o0, char* __restrict__ o1)
{
    const int sel = blockIdx.x & 1;
    const float4* w4 = (const float4*)(sel ? w1 : w0);
    char4* o4 = (char4*)(sel ? o1 : o0);
    float s = (float)(sums[sel] * inv_count);
    s = fmaxf(s, 1e-5f);
    const float t0 = 0.5f * s;
    const int b = blockIdx.x >> 1, nb = gridDim.x >> 1;
    for (int i = b * blockDim.x + threadIdx.x; i < n4; i += nb * blockDim.x) {
        float4 v = w4[i];
        char4 c;
        c.x = (fabsf(v.x) > t0) ? (v.x > 0.0f ? 1 : -1) : 0;
        c.y = (fabsf(v.y) > t0) ? (v.y > 0.0f ? 1 : -1) : 0;
        c.z = (fabsf(v.z) > t0) ? (v.z > 0.0f ? 1 : -1) : 0;
        c.w = (fabsf(v.w) > t0) ? (v.w > 0.0f ? 1 : -1) : 0;
        o4[i] = c;
    }
}

// ---------------- in-register H_16 butterfly helper ----------------
template<int NS>
__device__ __forceinline__ void hreg(float* v)
{
    #pragma unroll
    for (int h = 1; h < (1 << NS); h <<= 1)
        #pragma unroll
        for (int i = 0; i < 16; i++)
            if ((i & h) == 0) { float a = v[i], b = v[i + h]; v[i] = a + b; v[i + h] = a - b; }
}

// LDS element swizzle: logical float index e -> physical float index.
// 16-float rows; chunk (4 floats) XORed with (row>>1)&3.
__device__ __forceinline__ int lswz(int e)
{
    const int r16 = e >> 4;
    return r16 * 16 + 4 * (((e >> 2) & 3) ^ ((r16 >> 1) & 3)) + (e & 3);
}

// ---------------- FWHT + per-token absmax int8 quant (3-phase register FWHT) ----
template<int N, int TOKS>
__global__ __launch_bounds__(256) void fwht_quant_kernel(
    const float* __restrict__ in, long in_stride,
    char* __restrict__ outq, long out_stride,
    float* __restrict__ scales)
{
    constexpr int L = 256 / TOKS;          // threads per token (128 or 256)
    static_assert(N == 16 * L, "N must be 16*threads-per-token");
    __shared__ float sx[TOKS * N];
    __shared__ float red[4];

    const int tid = threadIdx.x;
    const int tk  = tid / L;
    const int lt  = tid % L;
    const long tok = (long)blockIdx.x * TOKS + tk;
    const float* row = in + tok * in_stride;
    float* s = sx + tk * N;

    float v[16];
    {
        const float4* r4 = (const float4*)(row + (size_t)lt * 16);
        float4 a[4];
        #pragma unroll
        for (int i = 0; i < 4; i++) a[i] = r4[i];
        #pragma unroll
        for (int i = 0; i < 4; i++) {
            v[4*i] = a[i].x; v[4*i+1] = a[i].y; v[4*i+2] = a[i].z; v[4*i+3] = a[i].w;
        }
    }
    hreg<4>(v);                            // h = 1,2,4,8
    {
        const int psw = (lt >> 1) & 3;     // == (row16>>1)&3 for row16 = lt
        #pragma unroll
        for (int i = 0; i < 4; i++)
            *(float4*)(s + lt * 16 + 4 * (i ^ psw)) =
                make_float4(v[4*i], v[4*i+1], v[4*i+2], v[4*i+3]);
    }
    __syncthreads();

    const int o = lt & 15, ss = lt >> 4;
    #pragma unroll
    for (int j = 0; j < 16; j++) v[j] = s[lswz(o + 256 * ss + 16 * j)];
    hreg<(L == 256) ? 4 : 3>(v);           // h = 16..128 (L=256) or 16..64 (L=128)
    #pragma unroll
    for (int j = 0; j < 16; j++) s[lswz(o + 256 * ss + 16 * j)] = v[j];
    __syncthreads();

    #pragma unroll
    for (int j = 0; j < 16; j++) v[j] = s[lswz(o + 16 * ss + L * j)];
    hreg<4>(v);                            // top 4 stages

    const float rn = 1.0f / sqrtf((float)N);
    float m = 0.0f;
    #pragma unroll
    for (int j = 0; j < 16; j++) { v[j] *= rn; m = fmaxf(m, fabsf(v[j])); }
    for (int off = 32; off > 0; off >>= 1) m = fmaxf(m, __shfl_down(m, off, 64));
    if ((tid & 63) == 0) red[tid >> 6] = m;
    __syncthreads();
    float mm;
    if (TOKS == 1) mm = fmaxf(fmaxf(red[0], red[1]), fmaxf(red[2], red[3]));
    else           mm = fmaxf(red[2 * tk], red[2 * tk + 1]);
    mm = fmaxf(mm, 1e-5f);
    const float sc = 127.0f / mm;
    if (lt == 0) scales[tok] = sc;
    __syncthreads();                       // sx about to be reused as i8 buffer

    char* ct = (char*)sx + tk * N;
    #pragma unroll
    for (int j = 0; j < 16; j++) {
        float q = fminf(fmaxf(rintf(v[j] * sc), -127.0f), 127.0f);
        ct[o + 16 * ss + L * j] = (char)q;
    }
    __syncthreads();
    int4* dst = (int4*)(outq + tok * out_stride);
    dst[lt] = ((const int4*)ct)[lt];
}

// ---------------- FWHT + quant, f16 input (N=4096, 1 token/block) ----------------
__global__ __launch_bounds__(256) void fwht_quant_f16_kernel(
    const __half* __restrict__ in, long in_stride,
    char* __restrict__ outq, long out_stride,
    float* __restrict__ scales)
{
    constexpr int N = 4096, L = 256;
    __shared__ float sx[N];
    __shared__ float red[4];

    const int lt = threadIdx.x;
    const long tok = blockIdx.x;
    const __half* row = in + tok * in_stride;
    float* s = sx;

    float v[16];
    {
        const int4* r4 = (const int4*)row;
        int4 q0 = r4[2 * lt], q1 = r4[2 * lt + 1];
        const __half2* h0 = (const __half2*)&q0;
        const __half2* h1 = (const __half2*)&q1;
        #pragma unroll
        for (int i = 0; i < 4; i++) {
            float2 f = __half22float2(h0[i]);
            v[2*i] = f.x; v[2*i+1] = f.y;
        }
        #pragma unroll
        for (int i = 0; i < 4; i++) {
            float2 f = __half22float2(h1[i]);
            v[8+2*i] = f.x; v[8+2*i+1] = f.y;
        }
    }
    hreg<4>(v);                            // h = 1,2,4,8
    {
        const int psw = (lt >> 1) & 3;
        #pragma unroll
        for (int i = 0; i < 4; i++)
            *(float4*)(s + lt * 16 + 4 * (i ^ psw)) =
                make_float4(v[4*i], v[4*i+1], v[4*i+2], v[4*i+3]);
    }
    __syncthreads();

    const int o = lt & 15, ss = lt >> 4;
    #pragma unroll
    for (int j = 0; j < 16; j++) v[j] = s[lswz(o + 256 * ss + 16 * j)];
    hreg<4>(v);                            // h = 16..128
    #pragma unroll
    for (int j = 0; j < 16; j++) s[lswz(o + 256 * ss + 16 * j)] = v[j];
    __syncthreads();

    #pragma unroll
    for (int j = 0; j < 16; j++) v[j] = s[lswz(o + 16 * ss + L * j)];
    hreg<4>(v);                            // h = 256..2048

    const float rn = 1.0f / sqrtf((float)N);
    float m = 0.0f;
    #pragma unroll
    for (int j = 0; j < 16; j++) { v[j] *= rn; m = fmaxf(m, fabsf(v[j])); }
    for (int off = 32; off > 0; off >>= 1) m = fmaxf(m, __shfl_down(m, off, 64));
    if ((lt & 63) == 0) red[lt >> 6] = m;
    __syncthreads();
    float mm = fmaxf(fmaxf(red[0], red[1]), fmaxf(red[2], red[3]));
    mm = fmaxf(mm, 1e-5f);
    const float sc = 127.0f / mm;
    if (lt == 0) scales[tok] = sc;
    __syncthreads();                       // sx about to be reused as i8 buffer

    char* ct = (char*)sx;
    #pragma unroll
    for (int j = 0; j < 16; j++) {
        float q = fminf(fmaxf(rintf(v[j] * sc), -127.0f), 127.0f);
        ct[o + 16 * ss + L * j] = (char)q;
    }
    __syncthreads();
    int4* dst = (int4*)(outq + tok * out_stride);
    dst[lt] = ((const int4*)ct)[lt];
}

// ---------------- i8 MFMA GEMM, 128x128 tile, 4 waves, multi-block overlap ----------
// Per-wave 64x64 output -> acc = 64 AGPR (vs 128 at 256^2): total regs/wave ~<=170
// -> 3 waves/SIMD -> 3 independent blocks/CU. Inter-block wave scheduling overlaps
// one block's LDS reads with another's MFMA (the m114 mechanism) -- no barrier
// lockstep trap. 2-deep LDS ring (32 KB); stage(t+1) issued BEFORE compute(t) so
// the GLL latency hides under ~500 cyc of reads+MFMA; drain+barrier at loop end.
// LDS XOR swizzle: pre-swizzled global source + swizzled ds_read (dest linear).
#define BM 128
#define BN 128
#define BK 64

__global__ __launch_bounds__(256, 3) void gemm_bt_kernel(
    const char* __restrict__ A, int lda,
    const char* __restrict__ B, int ldb,
    void* __restrict__ Cv, int ldc,
    int K, int lognx,
    const float* __restrict__ sx,
    const double* __restrict__ wsum, double inv_count,
    int do_relu2, int out_f16)
{
    __shared__ __align__(16) char As[2][BM * BK];   // 2 x 8 KB
    __shared__ __align__(16) char Bs[2][BN * BK];   // 2 x 8 KB

    // XCD row-band swizzle (grid % 8 == 0 -> bijective); blocks sharing an A-row
    // panel (same by, all bx) land on one XCD -> A panel stays L2-resident.
    const int bid = blockIdx.x;
    const int xcd = bid & 7;
    const int n = bid >> 3;
    const int nper = gridDim.x >> 3;
    const int bx = n & ((1 << lognx) - 1);
    const int by = xcd * (nper >> lognx) + (n >> lognx);
    const int row0 = by * BM;
    const int col0 = bx * BN;

    const int tid = threadIdx.x;
    const int lane = tid & 63;
    const int w = tid >> 6;          // 4 waves
    const int wr = w >> 1;           // 0..1 : 64-row band
    const int wc = w & 1;            // 0..1 : 64-col band

    i32x4 acc[4][4] = {};            // 64 AGPR

    // ---- staging addressing: linear LDS dest, swizzled global source ----
    const int srow = w * 16 + (lane >> 2);                    // 0..63
    const int sseg = ((lane & 3) ^ ((lane >> 3) & 3)) << 4;
    const char* Ag0 = A + (size_t)(row0 + srow) * lda + sseg;
    const char* Ag1 = Ag0 + (size_t)64 * lda;
    const char* Bg0 = B + (size_t)(col0 + srow) * ldb + sseg;
    const char* Bg1 = Bg0 + (size_t)64 * ldb;
    const int wdst = w * 1024;       // wave's 16-row chunk within an 8 KB half

    // ---- fragment read addressing (swizzled) ----
    const int fr = lane & 15;
    const int fks = lane >> 4;
    const int rsw = ((fks ^ ((fr >> 1) & 3)) << 4);
    const int aoff = (wr * 64 + fr) * BK + rsw;    // + i*1024
    const int boff = (wc * 64 + fr) * BK + rsw;    // + j*1024

    const int NT = K >> 6;           // 32 (GEMM1) / 64 (GEMM2)

    auto stage = [&](int tt) {
        const int sb = tt & 1;
        const int ko = tt * BK;
        GLL16(Ag0 + ko, &As[sb][wdst]);
        GLL16(Ag1 + ko, &As[sb][wdst + 4096]);
        GLL16(Bg0 + ko, &Bs[sb][wdst]);
        GLL16(Bg1 + ko, &Bs[sb][wdst + 4096]);
    };
    auto compute = [&](int t) __attribute__((always_inline)) {
        const char* as = As[t & 1];
        const char* bs = Bs[t & 1];
        i32x4 af[4], bf[4];
        #pragma unroll
        for (int i = 0; i < 4; ++i) af[i] = *(const i32x4*)(as + aoff + i * 1024);
        #pragma unroll
        for (int j = 0; j < 4; ++j) bf[j] = *(const i32x4*)(bs + boff + j * 1024);
        __builtin_amdgcn_s_setprio(1);
        #pragma unroll
        for (int i = 0; i < 4; ++i)
            #pragma unroll
            for (int j = 0; j < 4; ++j)
                acc[i][j] = __builtin_amdgcn_mfma_i32_16x16x64_i8(af[i], bf[j], acc[i][j], 0, 0, 0);
        __builtin_amdgcn_s_setprio(0);
    };

    stage(0);
    asm volatile("s_waitcnt vmcnt(0)" ::: "memory");
    __builtin_amdgcn_s_barrier();
    CFENCE();

    for (int t = 0; t < NT - 1; ++t) {
        stage(t + 1);                // issue first: latency hides under compute(t)
        compute(t);
        asm volatile("s_waitcnt vmcnt(0)" ::: "memory");   // own 4 loads landed
        __builtin_amdgcn_s_barrier();
        CFENCE();
    }
    compute(NT - 1);

    // epilogue: out = (float)acc * s_w / scale_x[row]; optional relu^2; f32 or f16
    float sw = (float)(wsum[0] * inv_count);
    sw = fmaxf(sw, 1e-5f);
    const int qd = lane >> 4;
    if (out_f16) {
        __half* C = (__half*)Cv;
        #pragma unroll
        for (int i = 0; i < 4; ++i) {
            #pragma unroll
            for (int r = 0; r < 4; ++r) {
                int rowm = row0 + wr * 64 + i * 16 + qd * 4 + r;
                float esc = sw / sx[rowm];
                __half* crow = C + (size_t)rowm * ldc + col0 + wc * 64;
                #pragma unroll
                for (int j = 0; j < 4; ++j) {
                    float v = (float)acc[i][j][r] * esc;
                    if (do_relu2) { v = fmaxf(v, 0.0f); v = v * v; }
                    crow[j * 16 + fr] = __float2half(v);
                }
            }
        }
    } else {
        float* C = (float*)Cv;
        #pragma unroll
        for (int i = 0; i < 4; ++i) {
            #pragma unroll
            for (int r = 0; r < 4; ++r) {
                int rowm = row0 + wr * 64 + i * 16 + qd * 4 + r;
                float esc = sw / sx[rowm];
                float* crow = C + (size_t)rowm * ldc + col0 + wc * 64;
                #pragma unroll
                for (int j = 0; j < 4; ++j) {
                    float v = (float)acc[i][j][r] * esc;
                    if (do_relu2) { v = fmaxf(v, 0.0f); v = v * v; }
                    crow[j * 16 + fr] = v;
                }
            }
        }
    }
}

extern "C" void kernel_launch(void* const* d_in, const int* in_sizes, int n_in,
                              void* d_out, int out_size, void* d_ws, size_t ws_size,
                              hipStream_t stream)
{
    const float* X   = (const float*)d_in[0];   // (4,2048,2048) f32
    const float* Wup = (const float*)d_in[1];   // (4096,2048)   f32
    const float* Wdn = (const float*)d_in[2];   // (2048,4096)   f32
    float* out = (float*)d_out;                 // (4,2048,2048) f32

    const int Mtok = 8192, H = 2048, I = 4096;
    const int NW = H * I;                       // 8388608 = 2^23 weights per tensor

    // workspace layout
    char* ws = (char*)d_ws;
    double* sums = (double*)ws;                                  // 2 doubles
    float* sx1 = (float*)(ws + 1024);                            // 8192 f32
    float* sx2 = (float*)(ws + 1024 + 32768);                    // 8192 f32
    char* wqup = ws + (1 << 20);                                 // 8.4 MB (i8)
    char* wqdn = wqup + (size_t)NW;                              // 8.4 MB
    char* xq1  = wqdn + (size_t)NW;                              // 16.8 MB (i8)
    char* hbuf = xq1 + (size_t)Mtok * H;                         // 67 MB (h f16; xq2 i8 overlaid per-row)

    hipMemsetAsync(sums, 0, 16, stream);
    abs_sum2_kernel<<<1024, 256, 0, stream>>>(Wup, Wdn, NW / 4, sums);
    const double invc = 1.0 / (double)NW;       // exactly 2^-23
    wquant2_kernel<<<2048, 256, 0, stream>>>(Wup, Wdn, NW / 4, sums, invc, wqup, wqdn);

    // stage 1: FWHT(H=2048) + quant, 2 tokens/block
    fwht_quant_kernel<2048, 2><<<Mtok / 2, 256, 0, stream>>>(X, H, xq1, H, sx1);
    // GEMM1 + relu^2 fused -> hbuf (f16, ld=I); grid 32x64 tiles -> 1-D swizzled, lognx=5
    gemm_bt_kernel<<<(I / BN) * (Mtok / BM), 256, 0, stream>>>(
        xq1, H, wqup, H, hbuf, I, H, 5, sx1, &sums[0], invc, 1, 1);
    // stage 2: FWHT(I=4096) from f16 + quant; xq2 (i8) overlaid on hbuf rows (stride 2*I bytes)
    fwht_quant_f16_kernel<<<Mtok, 256, 0, stream>>>((const __half*)hbuf, I, hbuf, 2 * I, sx2);
    // GEMM2 -> out (f32); grid 16x64 tiles -> 1-D swizzled, lognx=4
    gemm_bt_kernel<<<(H / BN) * (Mtok / BM), 256, 0, stream>>>(
        (const char*)hbuf, 2 * I, wqdn, I, out, H, I, 4, sx2, &sums[1], invc, 0, 0);
}